// Round 1
// baseline (2620.482 us; speedup 1.0000x reference)
//
#include <hip/hip_runtime.h>
#include <math.h>

#define N_B 4
#define IMG 192

// ---------------- down path ----------------
__global__ void k_d1(const float* __restrict__ x, const float* __restrict__ w,
                     float* __restrict__ out) {
  int idx = blockIdx.x * 256 + threadIdx.x;            // (4,16,48,48)
  if (idx >= N_B * 16 * 48 * 48) return;
  int xq = idx % 48; int t = idx / 48; int yq = t % 48; t /= 48;
  int oc = t % 16; int b = t / 16;
  const float* xp = x + (b * IMG + yq * 4) * IMG + xq * 4;
  const float* wp = w + oc * 16;
  float s = 0.f;
#pragma unroll
  for (int dy = 0; dy < 4; ++dy)
#pragma unroll
    for (int dx = 0; dx < 4; ++dx)
      s = fmaf(xp[dy * IMG + dx], wp[dy * 4 + dx], s);
  out[idx] = fmaxf(s, 0.f);
}

__global__ void k_d2(const float* __restrict__ h1, const float* __restrict__ w,
                     float* __restrict__ out) {
  int idx = blockIdx.x * 256 + threadIdx.x;            // (4,256,12,12)
  if (idx >= N_B * 256 * 12 * 12) return;
  int xq = idx % 12; int t = idx / 12; int yq = t % 12; t /= 12;
  int oc = t % 256; int b = t / 256;
  float s = 0.f;
  for (int ci = 0; ci < 16; ++ci) {
    const float* ip = h1 + ((b * 16 + ci) * 48 + yq * 4) * 48 + xq * 4;
    const float* wp = w + (oc * 16 + ci) * 16;
#pragma unroll
    for (int dy = 0; dy < 4; ++dy)
#pragma unroll
      for (int dx = 0; dx < 4; ++dx)
        s = fmaf(ip[dy * 48 + dx], wp[dy * 4 + dx], s);
  }
  out[idx] = fmaxf(s, 0.f);
}

__global__ void k_d3(const float* __restrict__ h2, const float* __restrict__ w,
                     float* __restrict__ out) {
  int idx = blockIdx.x * 256 + threadIdx.x;            // (4,1024,6,6)
  if (idx >= N_B * 1024 * 6 * 6) return;
  int xq = idx % 6; int t = idx / 6; int yq = t % 6; t /= 6;
  int oc = t % 1024; int b = t / 1024;
  float s = 0.f;
  for (int ci = 0; ci < 256; ++ci) {
    const float* ip = h2 + ((b * 256 + ci) * 12 + yq * 2) * 12 + xq * 2;
    const float* wp = w + (oc * 256 + ci) * 4;
    s = fmaf(ip[0], wp[0], s);
    s = fmaf(ip[1], wp[1], s);
    s = fmaf(ip[12], wp[2], s);
    s = fmaf(ip[13], wp[3], s);
  }
  out[idx] = fmaxf(s, 0.f);
}

// d4 (1x1, no bias) + STE quantize: writes x4 (to d_out tail), xr and t0 (=xr)
__global__ void k_d4q(const float* __restrict__ h3, const float* __restrict__ w,
                      float* __restrict__ x4_out, float* __restrict__ xr,
                      float* __restrict__ t0) {
  int idx = blockIdx.x * 256 + threadIdx.x;            // (4,154,36)
  if (idx >= N_B * 154 * 36) return;
  int p = idx % 36; int t = idx / 36; int oc = t % 154; int b = t / 154;
  const float* ip = h3 + b * 1024 * 36 + p;
  const float* wp = w + oc * 1024;
  float s = 0.f;
  for (int ci = 0; ci < 1024; ++ci) s = fmaf(ip[ci * 36], wp[ci], s);
  x4_out[idx] = s;
  float q = floorf(s / 0.01f) * 0.01f;
  xr[idx] = q;
  t0[idx] = q;
}

// quant-compensation step: tout = relu(W*tin + b) + tin (+ xr)  [1x1 conv, 154ch]
__global__ void k_qcm(const float* __restrict__ tin, const float* __restrict__ w,
                      const float* __restrict__ bias, const float* __restrict__ xr,
                      float* __restrict__ tout, float* __restrict__ out2) {
  int idx = blockIdx.x * 256 + threadIdx.x;            // (4,154,36)
  if (idx >= N_B * 154 * 36) return;
  int p = idx % 36; int t = idx / 36; int oc = t % 154; int b = t / 154;
  const float* ip = tin + b * 154 * 36 + p;
  const float* wp = w + oc * 154;
  float s = bias[oc];
  for (int ci = 0; ci < 154; ++ci) s = fmaf(ip[ci * 36], wp[ci], s);
  float v = fmaxf(s, 0.f) + tin[idx];
  if (xr) v += xr[idx];
  tout[idx] = v;
  if (out2) out2[idx] = v;
}

// up 1x1 conv (154->1024) fused with depth_to_space(bs=32): y (4,1,192,192)
__global__ void k_up(const float* __restrict__ xc, const float* __restrict__ w,
                     const float* __restrict__ bias, float* __restrict__ y) {
  int idx = blockIdx.x * 256 + threadIdx.x;            // (4,192,192)
  if (idx >= N_B * IMG * IMG) return;
  int X = idx % IMG; int t = idx / IMG; int Y = t % IMG; int b = t / IMG;
  int h = Y >> 5, i = Y & 31, wq = X >> 5, j = X & 31;
  int co = i * 32 + j;
  const float* ip = xc + b * 154 * 36 + h * 6 + wq;
  const float* wp = w + co * 154;
  float s = bias[co];
  for (int ci = 0; ci < 154; ++ci) s = fmaf(ip[ci * 36], wp[ci], s);
  y[idx] = s;
}

// c1: 3x3 conv 1->64 + prelu
__global__ void k_c1(const float* __restrict__ y, const float* __restrict__ w,
                     const float* __restrict__ bias, const float* __restrict__ a_p,
                     float* __restrict__ out) {
  int idx = blockIdx.x * 256 + threadIdx.x;            // (4,64,192,192)
  if (idx >= N_B * 64 * IMG * IMG) return;
  int X = idx % IMG; int t = idx / IMG; int Y = t % IMG; t /= IMG;
  int oc = t % 64; int b = t / 64;
  const float* wp = w + oc * 9;
  float a = *a_p;
  float s = bias[oc];
#pragma unroll
  for (int dy = -1; dy <= 1; ++dy) {
    int gy = Y + dy;
    if ((unsigned)gy >= (unsigned)IMG) continue;
#pragma unroll
    for (int dx = -1; dx <= 1; ++dx) {
      int gx = X + dx;
      if ((unsigned)gx >= (unsigned)IMG) continue;
      s = fmaf(y[(b * IMG + gy) * IMG + gx], wp[(dy + 1) * 3 + (dx + 1)], s);
    }
  }
  out[idx] = s >= 0.f ? s : a * s;
}

// ------------- tiled 3x3 conv, 64 in-ch, OCPB out-ch per block -------------
#define TW 32
#define TH 8
#define CHUNK 16

template <int OCPB>
__global__ __launch_bounds__(256) void k_conv3x3(
    const float* __restrict__ in0, const float* __restrict__ in1, int in1_mode,
    const float* __restrict__ w, const float* __restrict__ bias,
    const float* __restrict__ a_p, float* __restrict__ out, int oc_groups) {
  __shared__ float smem[CHUNK * (TH + 2) * (TW + 2)];
  const int IC = 64;
  int tid = threadIdx.x;
  int x0 = blockIdx.x * TW, y0 = blockIdx.y * TH;
  int g = blockIdx.z % oc_groups;
  int b = blockIdx.z / oc_groups;
  int ocbase = g * OCPB;
  int tx = tid & 31, ty = tid >> 5;

  float acc[OCPB];
#pragma unroll
  for (int i = 0; i < OCPB; ++i) acc[i] = 0.f;

  for (int cb = 0; cb < IC; cb += CHUNK) {
    __syncthreads();
    for (int sidx = tid; sidx < CHUNK * (TH + 2) * (TW + 2); sidx += 256) {
      int ci = sidx / ((TH + 2) * (TW + 2));
      int r = sidx % ((TH + 2) * (TW + 2));
      int iy = r / (TW + 2), ix = r % (TW + 2);
      int gy = y0 - 1 + iy, gx = x0 - 1 + ix;
      float v = 0.f;
      if ((unsigned)gy < (unsigned)IMG && (unsigned)gx < (unsigned)IMG) {
        int gi = ((b * IC + cb + ci) * IMG + gy) * IMG + gx;
        v = in0[gi];
        if (in1_mode == 2) v += in1[gi];
        else if (in1_mode == 1) v += in1[(b * IMG + gy) * IMG + gx];
      }
      smem[sidx] = v;
    }
    __syncthreads();
    for (int ci = 0; ci < CHUNK; ++ci) {
      const float* sp = smem + ci * (TH + 2) * (TW + 2) + ty * (TW + 2) + tx;
      float r00 = sp[0], r01 = sp[1], r02 = sp[2];
      float r10 = sp[TW + 2], r11 = sp[TW + 3], r12 = sp[TW + 4];
      float r20 = sp[2 * (TW + 2)], r21 = sp[2 * (TW + 2) + 1], r22 = sp[2 * (TW + 2) + 2];
      const float* wp = w + ((size_t)ocbase * IC + (cb + ci)) * 9;
#pragma unroll
      for (int oc = 0; oc < OCPB; ++oc) {
        const float* wq = wp + oc * IC * 9;
        float s = acc[oc];
        s = fmaf(r00, wq[0], s);
        s = fmaf(r01, wq[1], s);
        s = fmaf(r02, wq[2], s);
        s = fmaf(r10, wq[3], s);
        s = fmaf(r11, wq[4], s);
        s = fmaf(r12, wq[5], s);
        s = fmaf(r20, wq[6], s);
        s = fmaf(r21, wq[7], s);
        s = fmaf(r22, wq[8], s);
        acc[oc] = s;
      }
    }
  }

  bool has_prelu = (a_p != nullptr);
  float a = has_prelu ? *a_p : 0.f;
  int Y = y0 + ty, X = x0 + tx;
  int OC_total = oc_groups * OCPB;
#pragma unroll
  for (int oc = 0; oc < OCPB; ++oc) {
    float v = acc[oc] + bias[ocbase + oc];
    if (has_prelu) v = v >= 0.f ? v : a * v;
    out[((size_t)(b * OC_total + ocbase + oc) * IMG + Y) * IMG + X] = v;
  }
}

// ---------------------------------------------------------------------------
extern "C" void kernel_launch(void* const* d_in, const int* in_sizes, int n_in,
                              void* d_out, int out_size, void* d_ws, size_t ws_size,
                              hipStream_t stream) {
  const float* x    = (const float*)d_in[0];
  const float* d1_w = (const float*)d_in[2];
  const float* d2_w = (const float*)d_in[3];
  const float* d3_w = (const float*)d_in[4];
  const float* d4_w = (const float*)d_in[5];
  const float* q1_w = (const float*)d_in[6];
  const float* q1_b = (const float*)d_in[7];
  const float* q2_w = (const float*)d_in[8];
  const float* q2_b = (const float*)d_in[9];
  const float* q3_w = (const float*)d_in[10];
  const float* q3_b = (const float*)d_in[11];
  const float* up_w = (const float*)d_in[12];
  const float* up_b = (const float*)d_in[13];
  const float* c1_w = (const float*)d_in[14];
  const float* c1_b = (const float*)d_in[15];
  const float* c1_a = (const float*)d_in[16];
  const float* c2_w = (const float*)d_in[17];
  const float* c2_b = (const float*)d_in[18];
  const float* c2_a = (const float*)d_in[19];
  const float* c3_w = (const float*)d_in[20];
  const float* c3_b = (const float*)d_in[21];
  const float* c3_a = (const float*)d_in[22];
  const float* c4_w = (const float*)d_in[23];
  const float* c4_b = (const float*)d_in[24];
  const float* c4_a = (const float*)d_in[25];
  const float* c5_w = (const float*)d_in[26];
  const float* c5_b = (const float*)d_in[27];

  float* out = (float*)d_out;
  float* ws  = (float*)d_ws;

  // output layout: b5 (4*256*192*192) | x_comp (4*154*36) | x4 (4*154*36)
  const size_t B5   = (size_t)N_B * 256 * IMG * IMG;   // 37,748,736
  const size_t SML  = (size_t)N_B * 154 * 36;          // 22,176
  float* out_b5    = out;
  float* out_xcomp = out + B5;
  float* out_x4    = out + B5 + SML;

  // ws layout (floats)
  size_t off = 0;
  float* h1    = ws + off; off += (size_t)N_B * 16 * 48 * 48;    // 147,456
  float* h2    = ws + off; off += (size_t)N_B * 256 * 12 * 12;   // 147,456
  float* h3    = ws + off; off += (size_t)N_B * 1024 * 36;       // 147,456
  float* xr    = ws + off; off += SML;
  float* t_a   = ws + off; off += SML;
  float* t_b   = ws + off; off += SML;
  float* xcomp = ws + off; off += SML;
  float* ybuf  = ws + off; off += (size_t)N_B * IMG * IMG;       // 147,456
  float* bufA  = ws + off; off += (size_t)N_B * 64 * IMG * IMG;  // 9,437,184
  float* bufB  = ws + off; off += (size_t)N_B * 64 * IMG * IMG;
  float* bufC  = ws + off; off += (size_t)N_B * 64 * IMG * IMG;

  // ---- down path ----
  k_d1<<<(N_B * 16 * 48 * 48 + 255) / 256, 256, 0, stream>>>(x, d1_w, h1);
  k_d2<<<(N_B * 256 * 12 * 12 + 255) / 256, 256, 0, stream>>>(h1, d2_w, h2);
  k_d3<<<(N_B * 1024 * 36 + 255) / 256, 256, 0, stream>>>(h2, d3_w, h3);
  k_d4q<<<((int)SML + 255) / 256, 256, 0, stream>>>(h3, d4_w, out_x4, xr, t_a);

  // ---- quant compensation ----
  int qgrid = ((int)SML + 255) / 256;
  k_qcm<<<qgrid, 256, 0, stream>>>(t_a, q1_w, q1_b, nullptr, t_b, nullptr);
  k_qcm<<<qgrid, 256, 0, stream>>>(t_b, q2_w, q2_b, nullptr, t_a, nullptr);
  k_qcm<<<qgrid, 256, 0, stream>>>(t_a, q3_w, q3_b, xr, xcomp, out_xcomp);

  // ---- upsample + depth_to_space ----
  k_up<<<(N_B * IMG * IMG + 255) / 256, 256, 0, stream>>>(xcomp, up_w, up_b, ybuf);

  // ---- refinement CNN ----
  k_c1<<<(N_B * 64 * IMG * IMG + 255) / 256, 256, 0, stream>>>(ybuf, c1_w, c1_b, c1_a, bufA);

  dim3 cgrid(IMG / TW, IMG / TH, N_B * 2);      // 64 oc = 2 groups of 32
  // c2: in = b1 + y(broadcast)
  k_conv3x3<32><<<cgrid, 256, 0, stream>>>(bufA, ybuf, 1, c2_w, c2_b, c2_a, bufB, 2);
  // c3: in = b2 + b1
  k_conv3x3<32><<<cgrid, 256, 0, stream>>>(bufB, bufA, 2, c3_w, c3_b, c3_a, bufC, 2);
  // c4: in = b3 + b2   (b1/bufA dead now -> reuse for b4)
  k_conv3x3<32><<<cgrid, 256, 0, stream>>>(bufC, bufB, 2, c4_w, c4_b, c4_a, bufA, 2);
  // c5: in = b4 + b3, 256 oc = 8 groups, no prelu, straight to d_out
  dim3 cgrid5(IMG / TW, IMG / TH, N_B * 8);
  k_conv3x3<32><<<cgrid5, 256, 0, stream>>>(bufA, bufC, 2, c5_w, c5_b, nullptr, out_b5, 8);
}

// Round 2
// 519.785 us; speedup vs baseline: 5.0415x; 5.0415x over previous
//
#include <hip/hip_runtime.h>
#include <math.h>

#define N_B 4
#define IMG 192

typedef __attribute__((ext_vector_type(8))) short short8;
typedef __attribute__((ext_vector_type(4))) float f32x4;

__device__ __forceinline__ unsigned f2bf(float f) {
  unsigned u = __float_as_uint(f);
  return (u + 0x7fffu + ((u >> 16) & 1u)) >> 16;   // RNE to bf16 bits
}

// ---------------- down path (unchanged, small) ----------------
__global__ void k_d1(const float* __restrict__ x, const float* __restrict__ w,
                     float* __restrict__ out) {
  int idx = blockIdx.x * 256 + threadIdx.x;            // (4,16,48,48)
  if (idx >= N_B * 16 * 48 * 48) return;
  int xq = idx % 48; int t = idx / 48; int yq = t % 48; t /= 48;
  int oc = t % 16; int b = t / 16;
  const float* xp = x + (b * IMG + yq * 4) * IMG + xq * 4;
  const float* wp = w + oc * 16;
  float s = 0.f;
#pragma unroll
  for (int dy = 0; dy < 4; ++dy)
#pragma unroll
    for (int dx = 0; dx < 4; ++dx)
      s = fmaf(xp[dy * IMG + dx], wp[dy * 4 + dx], s);
  out[idx] = fmaxf(s, 0.f);
}

__global__ void k_d2(const float* __restrict__ h1, const float* __restrict__ w,
                     float* __restrict__ out) {
  int idx = blockIdx.x * 256 + threadIdx.x;            // (4,256,12,12)
  if (idx >= N_B * 256 * 12 * 12) return;
  int xq = idx % 12; int t = idx / 12; int yq = t % 12; t /= 12;
  int oc = t % 256; int b = t / 256;
  float s = 0.f;
  for (int ci = 0; ci < 16; ++ci) {
    const float* ip = h1 + ((b * 16 + ci) * 48 + yq * 4) * 48 + xq * 4;
    const float* wp = w + (oc * 16 + ci) * 16;
#pragma unroll
    for (int dy = 0; dy < 4; ++dy)
#pragma unroll
      for (int dx = 0; dx < 4; ++dx)
        s = fmaf(ip[dy * 48 + dx], wp[dy * 4 + dx], s);
  }
  out[idx] = fmaxf(s, 0.f);
}

__global__ void k_d3(const float* __restrict__ h2, const float* __restrict__ w,
                     float* __restrict__ out) {
  int idx = blockIdx.x * 256 + threadIdx.x;            // (4,1024,6,6)
  if (idx >= N_B * 1024 * 6 * 6) return;
  int xq = idx % 6; int t = idx / 6; int yq = t % 6; t /= 6;
  int oc = t % 1024; int b = t / 1024;
  float s = 0.f;
  for (int ci = 0; ci < 256; ++ci) {
    const float* ip = h2 + ((b * 256 + ci) * 12 + yq * 2) * 12 + xq * 2;
    const float* wp = w + (oc * 256 + ci) * 4;
    s = fmaf(ip[0], wp[0], s);
    s = fmaf(ip[1], wp[1], s);
    s = fmaf(ip[12], wp[2], s);
    s = fmaf(ip[13], wp[3], s);
  }
  out[idx] = fmaxf(s, 0.f);
}

__global__ void k_d4q(const float* __restrict__ h3, const float* __restrict__ w,
                      float* __restrict__ x4_out, float* __restrict__ xr,
                      float* __restrict__ t0) {
  int idx = blockIdx.x * 256 + threadIdx.x;            // (4,154,36)
  if (idx >= N_B * 154 * 36) return;
  int p = idx % 36; int t = idx / 36; int oc = t % 154; int b = t / 154;
  const float* ip = h3 + b * 1024 * 36 + p;
  const float* wp = w + oc * 1024;
  float s = 0.f;
  for (int ci = 0; ci < 1024; ++ci) s = fmaf(ip[ci * 36], wp[ci], s);
  x4_out[idx] = s;
  float q = floorf(s / 0.01f) * 0.01f;
  xr[idx] = q;
  t0[idx] = q;
}

__global__ void k_qcm(const float* __restrict__ tin, const float* __restrict__ w,
                      const float* __restrict__ bias, const float* __restrict__ xr,
                      float* __restrict__ tout, float* __restrict__ out2) {
  int idx = blockIdx.x * 256 + threadIdx.x;            // (4,154,36)
  if (idx >= N_B * 154 * 36) return;
  int p = idx % 36; int t = idx / 36; int oc = t % 154; int b = t / 154;
  const float* ip = tin + b * 154 * 36 + p;
  const float* wp = w + oc * 154;
  float s = bias[oc];
  for (int ci = 0; ci < 154; ++ci) s = fmaf(ip[ci * 36], wp[ci], s);
  float v = fmaxf(s, 0.f) + tin[idx];
  if (xr) v += xr[idx];
  tout[idx] = v;
  if (out2) out2[idx] = v;
}

__global__ void k_up(const float* __restrict__ xc, const float* __restrict__ w,
                     const float* __restrict__ bias, float* __restrict__ y) {
  int idx = blockIdx.x * 256 + threadIdx.x;            // (4,192,192)
  if (idx >= N_B * IMG * IMG) return;
  int X = idx % IMG; int t = idx / IMG; int Y = t % IMG; int b = t / IMG;
  int h = Y >> 5, i = Y & 31, wq = X >> 5, j = X & 31;
  int co = i * 32 + j;
  const float* ip = xc + b * 154 * 36 + h * 6 + wq;
  const float* wp = w + co * 154;
  float s = bias[co];
  for (int ci = 0; ci < 154; ++ci) s = fmaf(ip[ci * 36], wp[ci], s);
  y[idx] = s;
}

// c1: 3x3 conv 1->64 + prelu, thread-per-pixel, NHWC fp32 output
__global__ __launch_bounds__(256) void k_c1n(const float* __restrict__ y,
                                             const float* __restrict__ w,
                                             const float* __restrict__ bias,
                                             const float* __restrict__ a_p,
                                             float* __restrict__ out) {
  int idx = blockIdx.x * 256 + threadIdx.x;            // (4,192,192) pixels
  if (idx >= N_B * IMG * IMG) return;
  int X = idx % IMG; int t = idx / IMG; int Y = t % IMG; int b = t / IMG;
  float p[9];
#pragma unroll
  for (int dy = 0; dy < 3; ++dy)
#pragma unroll
    for (int dx = 0; dx < 3; ++dx) {
      int gy = Y + dy - 1, gx = X + dx - 1;
      p[dy * 3 + dx] = ((unsigned)gy < (unsigned)IMG && (unsigned)gx < (unsigned)IMG)
                           ? y[(b * IMG + gy) * IMG + gx]
                           : 0.f;
    }
  float a = *a_p;
  float* op = out + (size_t)idx * 64;
  for (int oc = 0; oc < 64; oc += 4) {
    float4 st;
    float* sp = &st.x;
#pragma unroll
    for (int j = 0; j < 4; ++j) {
      float s = bias[oc + j];
      const float* wq = w + (oc + j) * 9;
#pragma unroll
      for (int k = 0; k < 9; ++k) s = fmaf(p[k], wq[k], s);
      sp[j] = s >= 0.f ? s : a * s;
    }
    *(float4*)(op + oc) = st;
  }
}

// pack conv weights fp32 [oc][64][3][3] -> bf16 [tap][oc][64 ic]
__global__ __launch_bounds__(256) void k_wprep(const float* __restrict__ w,
                                               short* __restrict__ wbf, int OC) {
  int idx = blockIdx.x * 256 + threadIdx.x;
  if (idx >= OC * 64 * 9) return;
  int tap = idx % 9; int t = idx / 9; int ic = t % 64; int oc = t / 64;
  wbf[(tap * OC + oc) * 64 + ic] = (short)f2bf(w[idx]);
}

// ---- MFMA implicit-GEMM 3x3 conv, IC=64, 64 oc per block ----
// tile: 8 rows x 32 cols spatial (N dim), 64 oc (M dim). 4 waves.
// LDS: act[340 pixels][64 ic] bf16, XOR-swizzled (T2).
template <int IN1MODE, bool NCHW_OUT, bool HASPRELU>
__global__ __launch_bounds__(256) void k_conv3x3m(
    const float* __restrict__ in0, const float* __restrict__ in1,
    const short* __restrict__ wbf, const float* __restrict__ bias,
    const float* __restrict__ a_p, float* __restrict__ out, int ocg_count) {
  __shared__ __align__(16) char smem[340 * 128];
  int tid = threadIdx.x;
  int g = blockIdx.z % ocg_count, b = blockIdx.z / ocg_count;
  int x0 = blockIdx.x * 32, y0 = blockIdx.y * 8;
  int OCtot = ocg_count * 64;

  // ---- stage: global fp32 NHWC (+residual) -> bf16 LDS, swizzled ----
  for (int idx = tid; idx < 340 * 16; idx += 256) {
    int pix = idx >> 4, icq = idx & 15;
    int py = pix / 34, px = pix % 34;
    int gy = y0 - 1 + py, gx = x0 - 1 + px;
    float4 v = make_float4(0.f, 0.f, 0.f, 0.f);
    if ((unsigned)gy < (unsigned)IMG && (unsigned)gx < (unsigned)IMG) {
      int pbase = ((b * IMG + gy) * IMG + gx) * 64 + icq * 4;
      v = *(const float4*)(in0 + pbase);
      if (IN1MODE == 2) {
        float4 r = *(const float4*)(in1 + pbase);
        v.x += r.x; v.y += r.y; v.z += r.z; v.w += r.w;
      } else if (IN1MODE == 1) {
        float r = in1[(b * IMG + gy) * IMG + gx];
        v.x += r; v.y += r; v.z += r; v.w += r;
      }
    }
    unsigned lo = f2bf(v.x) | (f2bf(v.y) << 16);
    unsigned hi = f2bf(v.z) | (f2bf(v.w) << 16);
    int byte = (pix * 128 + icq * 8) ^ ((pix & 7) << 4);
    *(uint2*)(smem + byte) = make_uint2(lo, hi);
  }
  __syncthreads();

  int w = tid >> 6, lane = tid & 63, li = lane & 15, lg = lane >> 4;
  int row0 = 2 * w;                    // this wave's 2 spatial rows
  f32x4 acc[4][4];
#pragma unroll
  for (int mt = 0; mt < 4; ++mt)
#pragma unroll
    for (int nt = 0; nt < 4; ++nt) acc[mt][nt] = (f32x4){0.f, 0.f, 0.f, 0.f};

#pragma unroll
  for (int tap = 0; tap < 9; ++tap) {
    const int dy = tap / 3, dx = tap % 3;
#pragma unroll
    for (int ks = 0; ks < 2; ++ks) {
      short8 bfr[4];
#pragma unroll
      for (int nt = 0; nt < 4; ++nt) {
        int pix = (row0 + (nt >> 1) + dy) * 34 + (nt & 1) * 16 + dx + li;
        int byte = (pix * 128 + ks * 64 + lg * 16) ^ ((pix & 7) << 4);
        bfr[nt] = *(const short8*)(smem + byte);
      }
      short8 afr[4];
#pragma unroll
      for (int mt = 0; mt < 4; ++mt)
        afr[mt] = *(const short8*)(wbf +
            ((size_t)(tap * OCtot + g * 64 + mt * 16 + li) * 64 + ks * 32 + lg * 8));
#pragma unroll
      for (int mt = 0; mt < 4; ++mt)
#pragma unroll
        for (int nt = 0; nt < 4; ++nt)
          acc[mt][nt] = __builtin_amdgcn_mfma_f32_16x16x32_bf16(
              afr[mt], bfr[nt], acc[mt][nt], 0, 0, 0);
    }
  }

  // ---- epilogue: bias + prelu + store ----
  float a = HASPRELU ? *a_p : 0.f;
#pragma unroll
  for (int nt = 0; nt < 4; ++nt) {
    int gy = y0 + row0 + (nt >> 1);
    int gx = x0 + (nt & 1) * 16 + li;
#pragma unroll
    for (int mt = 0; mt < 4; ++mt) {
      int ocl = mt * 16 + lg * 4;
      float4 bv = *(const float4*)(bias + g * 64 + ocl);
      f32x4 v = acc[mt][nt];
      float r0 = v[0] + bv.x, r1 = v[1] + bv.y, r2 = v[2] + bv.z, r3 = v[3] + bv.w;
      if (HASPRELU) {
        r0 = r0 >= 0.f ? r0 : a * r0;
        r1 = r1 >= 0.f ? r1 : a * r1;
        r2 = r2 >= 0.f ? r2 : a * r2;
        r3 = r3 >= 0.f ? r3 : a * r3;
      }
      if (!NCHW_OUT) {
        *(float4*)(out + (size_t)((b * IMG + gy) * IMG + gx) * 64 + ocl) =
            make_float4(r0, r1, r2, r3);
      } else {
        size_t base = (((size_t)b * OCtot + g * 64 + ocl) * IMG + gy) * IMG + gx;
        out[base] = r0;
        out[base + (size_t)IMG * IMG] = r1;
        out[base + (size_t)2 * IMG * IMG] = r2;
        out[base + (size_t)3 * IMG * IMG] = r3;
      }
    }
  }
}

// ---------------------------------------------------------------------------
extern "C" void kernel_launch(void* const* d_in, const int* in_sizes, int n_in,
                              void* d_out, int out_size, void* d_ws, size_t ws_size,
                              hipStream_t stream) {
  const float* x    = (const float*)d_in[0];
  const float* d1_w = (const float*)d_in[2];
  const float* d2_w = (const float*)d_in[3];
  const float* d3_w = (const float*)d_in[4];
  const float* d4_w = (const float*)d_in[5];
  const float* q1_w = (const float*)d_in[6];
  const float* q1_b = (const float*)d_in[7];
  const float* q2_w = (const float*)d_in[8];
  const float* q2_b = (const float*)d_in[9];
  const float* q3_w = (const float*)d_in[10];
  const float* q3_b = (const float*)d_in[11];
  const float* up_w = (const float*)d_in[12];
  const float* up_b = (const float*)d_in[13];
  const float* c1_w = (const float*)d_in[14];
  const float* c1_b = (const float*)d_in[15];
  const float* c1_a = (const float*)d_in[16];
  const float* c2_w = (const float*)d_in[17];
  const float* c2_b = (const float*)d_in[18];
  const float* c2_a = (const float*)d_in[19];
  const float* c3_w = (const float*)d_in[20];
  const float* c3_b = (const float*)d_in[21];
  const float* c3_a = (const float*)d_in[22];
  const float* c4_w = (const float*)d_in[23];
  const float* c4_b = (const float*)d_in[24];
  const float* c4_a = (const float*)d_in[25];
  const float* c5_w = (const float*)d_in[26];
  const float* c5_b = (const float*)d_in[27];

  float* out = (float*)d_out;
  float* ws  = (float*)d_ws;

  const size_t B5  = (size_t)N_B * 256 * IMG * IMG;
  const size_t SML = (size_t)N_B * 154 * 36;
  float* out_b5    = out;
  float* out_xcomp = out + B5;
  float* out_x4    = out + B5 + SML;

  size_t off = 0;
  float* h1    = ws + off; off += (size_t)N_B * 16 * 48 * 48;
  float* h2    = ws + off; off += (size_t)N_B * 256 * 12 * 12;
  float* h3    = ws + off; off += (size_t)N_B * 1024 * 36;
  float* xr    = ws + off; off += SML;
  float* t_a   = ws + off; off += SML;
  float* t_b   = ws + off; off += SML;
  float* xcomp = ws + off; off += SML;
  float* ybuf  = ws + off; off += (size_t)N_B * IMG * IMG;
  float* bufA  = ws + off; off += (size_t)N_B * 64 * IMG * IMG;   // NHWC
  float* bufB  = ws + off; off += (size_t)N_B * 64 * IMG * IMG;   // NHWC
  float* bufC  = ws + off; off += (size_t)N_B * 64 * IMG * IMG;   // NHWC
  short* wb2   = (short*)(ws + off); off += 9 * 64 * 64 / 2;
  short* wb3   = (short*)(ws + off); off += 9 * 64 * 64 / 2;
  short* wb4   = (short*)(ws + off); off += 9 * 64 * 64 / 2;
  short* wb5   = (short*)(ws + off); off += 9 * 256 * 64 / 2;

  // weight packing (independent of data path)
  k_wprep<<<(9 * 64 * 64 + 255) / 256, 256, 0, stream>>>(c2_w, wb2, 64);
  k_wprep<<<(9 * 64 * 64 + 255) / 256, 256, 0, stream>>>(c3_w, wb3, 64);
  k_wprep<<<(9 * 64 * 64 + 255) / 256, 256, 0, stream>>>(c4_w, wb4, 64);
  k_wprep<<<(9 * 256 * 64 + 255) / 256, 256, 0, stream>>>(c5_w, wb5, 256);

  // ---- down path ----
  k_d1<<<(N_B * 16 * 48 * 48 + 255) / 256, 256, 0, stream>>>(x, d1_w, h1);
  k_d2<<<(N_B * 256 * 12 * 12 + 255) / 256, 256, 0, stream>>>(h1, d2_w, h2);
  k_d3<<<(N_B * 1024 * 36 + 255) / 256, 256, 0, stream>>>(h2, d3_w, h3);
  k_d4q<<<((int)SML + 255) / 256, 256, 0, stream>>>(h3, d4_w, out_x4, xr, t_a);

  // ---- quant compensation ----
  int qgrid = ((int)SML + 255) / 256;
  k_qcm<<<qgrid, 256, 0, stream>>>(t_a, q1_w, q1_b, nullptr, t_b, nullptr);
  k_qcm<<<qgrid, 256, 0, stream>>>(t_b, q2_w, q2_b, nullptr, t_a, nullptr);
  k_qcm<<<qgrid, 256, 0, stream>>>(t_a, q3_w, q3_b, xr, xcomp, out_xcomp);

  // ---- upsample + depth_to_space ----
  k_up<<<(N_B * IMG * IMG + 255) / 256, 256, 0, stream>>>(xcomp, up_w, up_b, ybuf);

  // ---- refinement CNN ----
  k_c1n<<<(N_B * IMG * IMG + 255) / 256, 256, 0, stream>>>(ybuf, c1_w, c1_b, c1_a, bufA);

  dim3 cg(IMG / 32, IMG / 8, N_B);
  k_conv3x3m<1, false, true><<<cg, 256, 0, stream>>>(bufA, ybuf, wb2, c2_b, c2_a, bufB, 1);
  k_conv3x3m<2, false, true><<<cg, 256, 0, stream>>>(bufB, bufA, wb3, c3_b, c3_a, bufC, 1);
  k_conv3x3m<2, false, true><<<cg, 256, 0, stream>>>(bufC, bufB, wb4, c4_b, c4_a, bufA, 1);
  dim3 cg5(IMG / 32, IMG / 8, N_B * 4);
  k_conv3x3m<2, true, false><<<cg5, 256, 0, stream>>>(bufA, bufC, wb5, c5_b, nullptr, out_b5, 4);
}

// Round 3
// 476.648 us; speedup vs baseline: 5.4977x; 1.0905x over previous
//
#include <hip/hip_runtime.h>
#include <math.h>

#define N_B 4
#define IMG 192

typedef __attribute__((ext_vector_type(8))) short short8;
typedef __attribute__((ext_vector_type(4))) float f32x4;

__device__ __forceinline__ unsigned f2bf(float f) {
  unsigned u = __float_as_uint(f);
  return (u + 0x7fffu + ((u >> 16) & 1u)) >> 16;   // RNE to bf16 bits
}
__device__ __forceinline__ float bf2f(unsigned b) {
  return __uint_as_float(b << 16);
}

// ---------------- down path ----------------
__global__ void k_d1(const float* __restrict__ x, const float* __restrict__ w,
                     float* __restrict__ out) {
  int idx = blockIdx.x * 256 + threadIdx.x;            // (4,16,48,48)
  if (idx >= N_B * 16 * 48 * 48) return;
  int xq = idx % 48; int t = idx / 48; int yq = t % 48; t /= 48;
  int oc = t % 16; int b = t / 16;
  const float* xp = x + (b * IMG + yq * 4) * IMG + xq * 4;
  const float* wp = w + oc * 16;
  float s = 0.f;
#pragma unroll
  for (int dy = 0; dy < 4; ++dy)
#pragma unroll
    for (int dx = 0; dx < 4; ++dx)
      s = fmaf(xp[dy * IMG + dx], wp[dy * 4 + dx], s);
  out[idx] = fmaxf(s, 0.f);
}

__global__ void k_d2(const float* __restrict__ h1, const float* __restrict__ w,
                     float* __restrict__ out) {
  int idx = blockIdx.x * 256 + threadIdx.x;            // (4,256,12,12)
  if (idx >= N_B * 256 * 12 * 12) return;
  int xq = idx % 12; int t = idx / 12; int yq = t % 12; t /= 12;
  int oc = t % 256; int b = t / 256;
  float s = 0.f;
  for (int ci = 0; ci < 16; ++ci) {
    const float* ip = h1 + ((b * 16 + ci) * 48 + yq * 4) * 48 + xq * 4;
    const float* wp = w + (oc * 16 + ci) * 16;
#pragma unroll
    for (int dy = 0; dy < 4; ++dy)
#pragma unroll
      for (int dx = 0; dx < 4; ++dx)
        s = fmaf(ip[dy * 48 + dx], wp[dy * 4 + dx], s);
  }
  out[idx] = fmaxf(s, 0.f);
}

// d3 writes TRANSPOSED: h3t[(b*36 + p)*1024 + oc]
__global__ void k_d3(const float* __restrict__ h2, const float* __restrict__ w,
                     float* __restrict__ out) {
  int idx = blockIdx.x * 256 + threadIdx.x;            // (4,1024,6,6)
  if (idx >= N_B * 1024 * 36) return;
  int xq = idx % 6; int t = idx / 6; int yq = t % 6; t /= 6;
  int oc = t % 1024; int b = t / 1024;
  float s = 0.f;
  for (int ci = 0; ci < 256; ++ci) {
    const float* ip = h2 + ((b * 256 + ci) * 12 + yq * 2) * 12 + xq * 2;
    const float* wp = w + (oc * 256 + ci) * 4;
    s = fmaf(ip[0], wp[0], s);
    s = fmaf(ip[1], wp[1], s);
    s = fmaf(ip[12], wp[2], s);
    s = fmaf(ip[13], wp[3], s);
  }
  out[(b * 36 + yq * 6 + xq) * 1024 + oc] = fmaxf(s, 0.f);
}

// fused: d4 (1x1) + STE quantize + 3x qcm + up-conv + depth_to_space
// one block per (b, pixel); 144 blocks, 256 threads
__global__ __launch_bounds__(256) void k_mid(
    const float* __restrict__ h3t, const float* __restrict__ d4_w,
    const float* __restrict__ q1_w, const float* __restrict__ q1_b,
    const float* __restrict__ q2_w, const float* __restrict__ q2_b,
    const float* __restrict__ q3_w, const float* __restrict__ q3_b,
    const float* __restrict__ up_w, const float* __restrict__ up_b,
    float* __restrict__ x4_out, float* __restrict__ xcomp_out,
    float* __restrict__ y_out) {
  __shared__ float hv[1024];
  __shared__ float tv[160];
  __shared__ float xrv[160];
  int blk = blockIdx.x;
  int b = blk / 36, p = blk % 36;
  int tid = threadIdx.x;
  for (int i = tid; i < 1024; i += 256) hv[i] = h3t[(size_t)blk * 1024 + i];
  __syncthreads();
  // ---- x4 = d4_w . hv ; quantize ----
  if (tid < 154) {
    const float* wp = d4_w + (size_t)tid * 1024;
    float a0 = 0.f, a1 = 0.f, a2 = 0.f, a3 = 0.f;
    for (int i = 0; i < 1024; i += 4) {
      a0 = fmaf(hv[i], wp[i], a0);
      a1 = fmaf(hv[i + 1], wp[i + 1], a1);
      a2 = fmaf(hv[i + 2], wp[i + 2], a2);
      a3 = fmaf(hv[i + 3], wp[i + 3], a3);
    }
    float s = (a0 + a1) + (a2 + a3);
    x4_out[(b * 154 + tid) * 36 + p] = s;
    float q = floorf(s / 0.01f) * 0.01f;
    xrv[tid] = q;
    tv[tid] = q;
  }
  __syncthreads();
  // ---- 3x quant-compensation ----
  const float* qw[3] = {q1_w, q2_w, q3_w};
  const float* qb[3] = {q1_b, q2_b, q3_b};
  for (int l = 0; l < 3; ++l) {
    float s = 0.f;
    if (tid < 154) {
      const float* wp = qw[l] + (size_t)tid * 154;
      float a0 = 0.f, a1 = 0.f;
      int i = 0;
      for (; i + 1 < 154; i += 2) {
        a0 = fmaf(tv[i], wp[i], a0);
        a1 = fmaf(tv[i + 1], wp[i + 1], a1);
      }
      if (i < 154) a0 = fmaf(tv[i], wp[i], a0);
      s = qb[l][tid] + a0 + a1;
    }
    __syncthreads();
    if (tid < 154) tv[tid] = fmaxf(s, 0.f) + tv[tid];
    __syncthreads();
  }
  // ---- x_comp = t + xr ----
  if (tid < 154) {
    float xc = tv[tid] + xrv[tid];
    tv[tid] = xc;
    xcomp_out[(b * 154 + tid) * 36 + p] = xc;
  }
  __syncthreads();
  // ---- up conv + depth_to_space ----
  int h = p / 6, w6 = p % 6;
#pragma unroll
  for (int k = 0; k < 4; ++k) {
    int co = k * 256 + tid;
    const float* wp = up_w + (size_t)co * 154;
    float a0 = 0.f, a1 = 0.f;
    int i = 0;
    for (; i + 1 < 154; i += 2) {
      a0 = fmaf(tv[i], wp[i], a0);
      a1 = fmaf(tv[i + 1], wp[i + 1], a1);
    }
    if (i < 154) a0 = fmaf(tv[i], wp[i], a0);
    float s = up_b[co] + a0 + a1;
    int i32 = co >> 5, j = co & 31;
    y_out[(b * IMG + h * 32 + i32) * IMG + w6 * 32 + j] = s;
  }
}

// c1: 3x3 conv 1->64 + prelu; writes B1 = b1 (bf16 NHWC) and S1 = b1+y (bf16 NHWC)
__global__ __launch_bounds__(256) void k_c1b(const float* __restrict__ y,
                                             const float* __restrict__ w,
                                             const float* __restrict__ bias,
                                             const float* __restrict__ a_p,
                                             short* __restrict__ B1,
                                             short* __restrict__ S1) {
  int idx = blockIdx.x * 256 + threadIdx.x;            // pixels
  if (idx >= N_B * IMG * IMG) return;
  int X = idx % IMG; int t = idx / IMG; int Y = t % IMG; int b = t / IMG;
  float p[9];
#pragma unroll
  for (int dy = 0; dy < 3; ++dy)
#pragma unroll
    for (int dx = 0; dx < 3; ++dx) {
      int gy = Y + dy - 1, gx = X + dx - 1;
      p[dy * 3 + dx] = ((unsigned)gy < (unsigned)IMG && (unsigned)gx < (unsigned)IMG)
                           ? y[(b * IMG + gy) * IMG + gx]
                           : 0.f;
    }
  float a = *a_p;
  float yc = p[4];
  size_t base = (size_t)idx * 64;
  for (int oc = 0; oc < 64; oc += 8) {
    unsigned bw[4], sw[4];
#pragma unroll
    for (int j = 0; j < 8; ++j) {
      float s = bias[oc + j];
      const float* wq = w + (oc + j) * 9;
#pragma unroll
      for (int k = 0; k < 9; ++k) s = fmaf(p[k], wq[k], s);
      s = s >= 0.f ? s : a * s;
      float sv = s + yc;
      if (j & 1) { bw[j >> 1] |= f2bf(s) << 16; sw[j >> 1] |= f2bf(sv) << 16; }
      else       { bw[j >> 1] = f2bf(s);        sw[j >> 1] = f2bf(sv); }
    }
    *(uint4*)(B1 + base + oc) = make_uint4(bw[0], bw[1], bw[2], bw[3]);
    *(uint4*)(S1 + base + oc) = make_uint4(sw[0], sw[1], sw[2], sw[3]);
  }
}

// pack conv weights fp32 [oc][64][3][3] -> bf16 [tap][oc][64 ic]
__global__ __launch_bounds__(256) void k_wprep(const float* __restrict__ w,
                                               short* __restrict__ wbf, int OC) {
  int idx = blockIdx.x * 256 + threadIdx.x;
  if (idx >= OC * 64 * 9) return;
  int tap = idx % 9; int t = idx / 9; int ic = t % 64; int oc = t / 64;
  wbf[(tap * OC + oc) * 64 + ic] = (short)f2bf(w[idx]);
}

// ---- MFMA implicit-GEMM 3x3 conv, IC=64, bf16 NHWC input (pre-added resid) ----
// MODE 0: write bout=b_n (bf16) and sout=b_n+bprev (bf16), prelu
// MODE 1: write sout only, prelu
// MODE 2: write fout fp32 NCHW, no prelu
template <int MODE>
__global__ __launch_bounds__(256) void k_conv3x3b(
    const short* __restrict__ sin, const short* __restrict__ bprev,
    const short* __restrict__ wbf, const float* __restrict__ bias,
    const float* __restrict__ a_p, short* __restrict__ bout,
    short* __restrict__ sout, float* __restrict__ fout, int ocg_count) {
  __shared__ __align__(16) char smem[340 * 128];
  int tid = threadIdx.x;
  int g = blockIdx.z % ocg_count, b = blockIdx.z / ocg_count;
  int x0 = blockIdx.x * 32, y0 = blockIdx.y * 8;
  int OCtot = ocg_count * 64;

  // ---- stage: bf16 global -> bf16 LDS, XOR swizzled ----
  for (int idx = tid; idx < 340 * 8; idx += 256) {
    int pix = idx >> 3, icq = idx & 7;
    int py = pix / 34, px = pix % 34;
    int gy = y0 - 1 + py, gx = x0 - 1 + px;
    uint4 v = make_uint4(0u, 0u, 0u, 0u);
    if ((unsigned)gy < (unsigned)IMG && (unsigned)gx < (unsigned)IMG)
      v = *(const uint4*)(sin + (size_t)((b * IMG + gy) * IMG + gx) * 64 + icq * 8);
    int byte = (pix * 128 + icq * 16) ^ ((pix & 7) << 4);
    *(uint4*)(smem + byte) = v;
  }
  __syncthreads();

  int w = tid >> 6, lane = tid & 63, li = lane & 15, lg = lane >> 4;
  int row0 = 2 * w;
  f32x4 acc[4][4];
#pragma unroll
  for (int mt = 0; mt < 4; ++mt)
#pragma unroll
    for (int nt = 0; nt < 4; ++nt) acc[mt][nt] = (f32x4){0.f, 0.f, 0.f, 0.f};

#pragma unroll
  for (int tap = 0; tap < 9; ++tap) {
    const int dy = tap / 3, dx = tap % 3;
#pragma unroll
    for (int ks = 0; ks < 2; ++ks) {
      short8 bfr[4];
#pragma unroll
      for (int nt = 0; nt < 4; ++nt) {
        int pix = (row0 + (nt >> 1) + dy) * 34 + (nt & 1) * 16 + dx + li;
        int byte = (pix * 128 + ks * 64 + lg * 16) ^ ((pix & 7) << 4);
        bfr[nt] = *(const short8*)(smem + byte);
      }
      short8 afr[4];
#pragma unroll
      for (int mt = 0; mt < 4; ++mt)
        afr[mt] = *(const short8*)(wbf +
            ((size_t)(tap * OCtot + g * 64 + mt * 16 + li) * 64 + ks * 32 + lg * 8));
#pragma unroll
      for (int mt = 0; mt < 4; ++mt)
#pragma unroll
        for (int nt = 0; nt < 4; ++nt)
          acc[mt][nt] = __builtin_amdgcn_mfma_f32_16x16x32_bf16(
              afr[mt], bfr[nt], acc[mt][nt], 0, 0, 0);
    }
  }

  // ---- epilogue ----
  float a = (MODE != 2) ? *a_p : 0.f;
#pragma unroll
  for (int nt = 0; nt < 4; ++nt) {
    int gy = y0 + row0 + (nt >> 1);
    int gx = x0 + (nt & 1) * 16 + li;
#pragma unroll
    for (int mt = 0; mt < 4; ++mt) {
      int ocl = mt * 16 + lg * 4;
      float4 bv = *(const float4*)(bias + g * 64 + ocl);
      f32x4 v = acc[mt][nt];
      float r0 = v[0] + bv.x, r1 = v[1] + bv.y, r2 = v[2] + bv.z, r3 = v[3] + bv.w;
      if (MODE != 2) {
        r0 = r0 >= 0.f ? r0 : a * r0;
        r1 = r1 >= 0.f ? r1 : a * r1;
        r2 = r2 >= 0.f ? r2 : a * r2;
        r3 = r3 >= 0.f ? r3 : a * r3;
        size_t pi = (size_t)((b * IMG + gy) * IMG + gx) * 64 + ocl;
        if (MODE == 0)
          *(uint2*)(bout + pi) = make_uint2(f2bf(r0) | (f2bf(r1) << 16),
                                            f2bf(r2) | (f2bf(r3) << 16));
        uint2 pv = *(const uint2*)(bprev + pi);
        float s0 = r0 + bf2f(pv.x & 0xffffu);
        float s1 = r1 + bf2f(pv.x >> 16);
        float s2 = r2 + bf2f(pv.y & 0xffffu);
        float s3 = r3 + bf2f(pv.y >> 16);
        *(uint2*)(sout + pi) = make_uint2(f2bf(s0) | (f2bf(s1) << 16),
                                          f2bf(s2) | (f2bf(s3) << 16));
      } else {
        size_t base = (((size_t)b * OCtot + g * 64 + ocl) * IMG + gy) * IMG + gx;
        fout[base] = r0;
        fout[base + (size_t)IMG * IMG] = r1;
        fout[base + (size_t)2 * IMG * IMG] = r2;
        fout[base + (size_t)3 * IMG * IMG] = r3;
      }
    }
  }
}

// ---------------------------------------------------------------------------
extern "C" void kernel_launch(void* const* d_in, const int* in_sizes, int n_in,
                              void* d_out, int out_size, void* d_ws, size_t ws_size,
                              hipStream_t stream) {
  const float* x    = (const float*)d_in[0];
  const float* d1_w = (const float*)d_in[2];
  const float* d2_w = (const float*)d_in[3];
  const float* d3_w = (const float*)d_in[4];
  const float* d4_w = (const float*)d_in[5];
  const float* q1_w = (const float*)d_in[6];
  const float* q1_b = (const float*)d_in[7];
  const float* q2_w = (const float*)d_in[8];
  const float* q2_b = (const float*)d_in[9];
  const float* q3_w = (const float*)d_in[10];
  const float* q3_b = (const float*)d_in[11];
  const float* up_w = (const float*)d_in[12];
  const float* up_b = (const float*)d_in[13];
  const float* c1_w = (const float*)d_in[14];
  const float* c1_b = (const float*)d_in[15];
  const float* c1_a = (const float*)d_in[16];
  const float* c2_w = (const float*)d_in[17];
  const float* c2_b = (const float*)d_in[18];
  const float* c2_a = (const float*)d_in[19];
  const float* c3_w = (const float*)d_in[20];
  const float* c3_b = (const float*)d_in[21];
  const float* c3_a = (const float*)d_in[22];
  const float* c4_w = (const float*)d_in[23];
  const float* c4_b = (const float*)d_in[24];
  const float* c4_a = (const float*)d_in[25];
  const float* c5_w = (const float*)d_in[26];
  const float* c5_b = (const float*)d_in[27];

  float* out = (float*)d_out;
  float* ws  = (float*)d_ws;

  const size_t B5  = (size_t)N_B * 256 * IMG * IMG;
  const size_t SML = (size_t)N_B * 154 * 36;
  float* out_b5    = out;
  float* out_xcomp = out + B5;
  float* out_x4    = out + B5 + SML;

  const size_t PIX = (size_t)N_B * IMG * IMG;     // 147,456
  size_t off = 0;
  float* h1   = ws + off; off += (size_t)N_B * 16 * 48 * 48;
  float* h2   = ws + off; off += (size_t)N_B * 256 * 12 * 12;
  float* h3t  = ws + off; off += (size_t)N_B * 36 * 1024;
  float* ybuf = ws + off; off += PIX;
  short* sl0  = (short*)(ws + off); off += PIX * 64 / 2;
  short* sl1  = (short*)(ws + off); off += PIX * 64 / 2;
  short* sl2  = (short*)(ws + off); off += PIX * 64 / 2;
  short* sl3  = (short*)(ws + off); off += PIX * 64 / 2;
  short* wb2  = (short*)(ws + off); off += 9 * 64 * 64 / 2;
  short* wb3  = (short*)(ws + off); off += 9 * 64 * 64 / 2;
  short* wb4  = (short*)(ws + off); off += 9 * 64 * 64 / 2;
  short* wb5  = (short*)(ws + off); off += 9 * 256 * 64 / 2;

  // weight packing (independent)
  k_wprep<<<(9 * 64 * 64 + 255) / 256, 256, 0, stream>>>(c2_w, wb2, 64);
  k_wprep<<<(9 * 64 * 64 + 255) / 256, 256, 0, stream>>>(c3_w, wb3, 64);
  k_wprep<<<(9 * 64 * 64 + 255) / 256, 256, 0, stream>>>(c4_w, wb4, 64);
  k_wprep<<<(9 * 256 * 64 + 255) / 256, 256, 0, stream>>>(c5_w, wb5, 256);

  // ---- down path ----
  k_d1<<<(N_B * 16 * 48 * 48 + 255) / 256, 256, 0, stream>>>(x, d1_w, h1);
  k_d2<<<(N_B * 256 * 12 * 12 + 255) / 256, 256, 0, stream>>>(h1, d2_w, h2);
  k_d3<<<(N_B * 1024 * 36 + 255) / 256, 256, 0, stream>>>(h2, d3_w, h3t);

  // ---- fused d4 + quantize + qcm x3 + up + depth_to_space ----
  k_mid<<<N_B * 36, 256, 0, stream>>>(h3t, d4_w, q1_w, q1_b, q2_w, q2_b,
                                      q3_w, q3_b, up_w, up_b,
                                      out_x4, out_xcomp, ybuf);

  // ---- refinement CNN ----
  k_c1b<<<(int)((PIX + 255) / 256), 256, 0, stream>>>(ybuf, c1_w, c1_b, c1_a,
                                                      sl1 /*B1*/, sl0 /*S1*/);

  dim3 cg(IMG / 32, IMG / 8, N_B);
  // c2: in S1(sl0), bprev B1(sl1) -> B2(sl2), S2(sl3)
  k_conv3x3b<0><<<cg, 256, 0, stream>>>(sl0, sl1, wb2, c2_b, c2_a, sl2, sl3, nullptr, 1);
  // c3: in S2(sl3), bprev B2(sl2) -> B3(sl1), S3(sl0)
  k_conv3x3b<0><<<cg, 256, 0, stream>>>(sl3, sl2, wb3, c3_b, c3_a, sl1, sl0, nullptr, 1);
  // c4: in S3(sl0), bprev B3(sl1) -> S4(sl3)
  k_conv3x3b<1><<<cg, 256, 0, stream>>>(sl0, sl1, wb4, c4_b, c4_a, nullptr, sl3, nullptr, 1);
  // c5: in S4(sl3) -> d_out fp32 NCHW
  dim3 cg5(IMG / 32, IMG / 8, N_B * 4);
  k_conv3x3b<2><<<cg5, 256, 0, stream>>>(sl3, nullptr, wb5, c5_b, nullptr, nullptr, nullptr, out_b5, 4);
}